// Round 1
// baseline (132.365 us; speedup 1.0000x reference)
//
#include <hip/hip_runtime.h>

// Problem constants (fixed by reference)
#define BATCH 2
#define NPTS  2048
#define CIN   64
#define COUT  128
#define GD    14                 // padded grid dim: vox in [0,11], +off in [-1,12] -> +1 shift -> [0,13]
#define GD2   (GD*GD)            // 196
#define NCELL (GD*GD*GD)         // 2744
#define M     (BATCH*NPTS)       // 4096
#define VOXF  (BATCH*NCELL*CIN)  // 351232 floats
#define OUTF  (M*COUT)           // 524288 floats
#define PT    32                 // points per gemm tile
#define OFFG  9                  // offsets per split-K group (27 = 3 groups of 9)

// Kernel 1: zero voxel grid, compute padded cell ids, seed out with bias.
__global__ __launch_bounds__(256) void k_init(const float* __restrict__ points,
                                              const float* __restrict__ bias,
                                              float* __restrict__ voxgrid,
                                              int* __restrict__ cellid,
                                              float* __restrict__ out) {
    int idx = blockIdx.x * 256 + threadIdx.x;
    if (idx < VOXF) voxgrid[idx] = 0.0f;
    if (idx < M) {
        float px = points[idx*3 + 0];
        float py = points[idx*3 + 1];
        float pz = points[idx*3 + 2];
        // jnp astype(int32) truncates toward zero; points are in [0,12) so plain cast matches
        int vx = (int)px, vy = (int)py, vz = (int)pz;
        cellid[idx] = (vx + 1)*GD2 + (vy + 1)*GD + (vz + 1);
    }
    if (idx < OUTF) out[idx] = bias[idx & (COUT - 1)];
}

// Kernel 2: scatter-add features into the voxel grid. One thread per (point, cin).
__global__ __launch_bounds__(256) void k_scatter(const float* __restrict__ feat,
                                                 const int* __restrict__ cellid,
                                                 float* __restrict__ voxgrid) {
    int idx = blockIdx.x * 256 + threadIdx.x;   // [0, M*CIN)
    int g   = idx >> 6;                         // point index (CIN==64)
    int cin = idx & 63;
    int b   = g >> 11;                          // NPTS==2048
    int cell = cellid[g];
    atomicAdd(&voxgrid[((size_t)b*NCELL + cell)*CIN + cin], feat[idx]);
}

// Kernel 3: gather-GEMM. out[g, c] += sum_off sum_cin voxgrid[b, cell(g)+delta(off), cin] * W[off, cin, c]
// Tile: 32 points x 64 cout per block; thread = 2 points x 4 couts; split-K over 3 offset groups.
__global__ __launch_bounds__(256) void k_gemm(const float* __restrict__ voxgrid,
                                              const int* __restrict__ cellid,
                                              const float* __restrict__ weight,
                                              float* __restrict__ out) {
    __shared__ int   scell[PT];
    __shared__ float A[PT][CIN + 4];   // +4 pad: row stride 68 breaks 32-bank aliasing

    const int t     = threadIdx.x;
    const int tileP = blockIdx.x;      // 0..127
    const int chalf = blockIdx.y;      // 0..1
    const int og    = blockIdx.z;      // 0..2

    const int g0 = tileP * PT;         // tile fully inside one batch (32 | 2048)
    const int b  = g0 >> 11;
    const float* vg = voxgrid + (size_t)b * NCELL * CIN;

    if (t < PT) scell[t] = cellid[g0 + t];
    __syncthreads();

    const int clane = t & 15;
    const int prow  = t >> 4;          // 0..15
    const int c0    = chalf*64 + clane*4;
    const int p0    = prow*2, p1 = prow*2 + 1;

    float acc0[4] = {0.f, 0.f, 0.f, 0.f};
    float acc1[4] = {0.f, 0.f, 0.f, 0.f};

    for (int oo = 0; oo < OFFG; ++oo) {
        const int off = og*OFFG + oo;
        const int oi = off / 9, oj = (off / 3) % 3, ok = off % 3;
        const int delta = (oi - 1)*GD2 + (oj - 1)*GD + (ok - 1);

        __syncthreads();  // protect A reads of previous iteration
        // stage A: 32 rows x 64 floats = 512 float4 slots, 2 per thread
        #pragma unroll
        for (int s = t; s < PT*CIN/4; s += 256) {
            const int row = s >> 4;
            const int c4  = (s & 15) * 4;
            const float4 v = *(const float4*)&vg[(size_t)(scell[row] + delta)*CIN + c4];
            A[row][c4+0] = v.x; A[row][c4+1] = v.y; A[row][c4+2] = v.z; A[row][c4+3] = v.w;
        }
        __syncthreads();

        const float* wbase = weight + (size_t)off*CIN*COUT + c0;
        #pragma unroll 8
        for (int cin = 0; cin < CIN; ++cin) {
            const float a0 = A[p0][cin];
            const float a1 = A[p1][cin];
            const float4 w = *(const float4*)&wbase[(size_t)cin * COUT];
            acc0[0] += a0*w.x; acc0[1] += a0*w.y; acc0[2] += a0*w.z; acc0[3] += a0*w.w;
            acc1[0] += a1*w.x; acc1[1] += a1*w.y; acc1[2] += a1*w.z; acc1[3] += a1*w.w;
        }
    }

    const size_t o0 = (size_t)(g0 + p0)*COUT + c0;
    const size_t o1 = (size_t)(g0 + p1)*COUT + c0;
    #pragma unroll
    for (int k = 0; k < 4; ++k) {
        atomicAdd(&out[o0 + k], acc0[k]);
        atomicAdd(&out[o1 + k], acc1[k]);
    }
}

extern "C" void kernel_launch(void* const* d_in, const int* in_sizes, int n_in,
                              void* d_out, int out_size, void* d_ws, size_t ws_size,
                              hipStream_t stream) {
    (void)in_sizes; (void)n_in; (void)out_size; (void)ws_size;
    const float* points   = (const float*)d_in[0];  // (2,2048,3)
    const float* features = (const float*)d_in[1];  // (2,2048,64)
    const float* weight   = (const float*)d_in[2];  // (3,3,3,64,128)
    const float* bias     = (const float*)d_in[3];  // (128,)
    float* out = (float*)d_out;                     // (2,2048,128)

    float* voxgrid = (float*)d_ws;                         // VOXF floats
    int*   cellid  = (int*)((char*)d_ws + (size_t)VOXF*4); // M ints

    // 1) init: zero grid, cell ids, out = bias
    k_init<<<(OUTF + 255)/256, 256, 0, stream>>>(points, bias, voxgrid, cellid, out);
    // 2) scatter features into voxel grid
    k_scatter<<<(M*CIN + 255)/256, 256, 0, stream>>>(features, cellid, voxgrid);
    // 3) gather-GEMM with split-K atomics
    dim3 grid(M/PT, COUT/64, 27/OFFG);
    k_gemm<<<grid, 256, 0, stream>>>(voxgrid, cellid, weight, out);
}

// Round 2
// 80.764 us; speedup vs baseline: 1.6389x; 1.6389x over previous
//
#include <hip/hip_runtime.h>

// Problem constants (fixed by reference)
#define BATCH 2
#define NPTS  2048
#define CIN   64
#define COUT  128
#define GD    14                 // padded grid dim: vox in [0,11] -> +1 shift, halo -> [0,13]
#define GD2   (GD*GD)            // 196
#define NCELL (GD*GD*GD)         // 2744
#define M     (BATCH*NPTS)       // 4096
#define VOXF  (BATCH*NCELL*CIN)  // 351232 floats
#define WTEL  (27*COUT*CIN)      // 221184 bf16 elements (transposed weight)

typedef __bf16 bf16x8 __attribute__((ext_vector_type(8)));
typedef float  f32x4  __attribute__((ext_vector_type(4)));
typedef unsigned short us8 __attribute__((ext_vector_type(8)));

__device__ __forceinline__ unsigned short f2bf(float f) {
    unsigned u = __builtin_bit_cast(unsigned, f);
    return (unsigned short)((u + 0x7FFFu + ((u >> 16) & 1u)) >> 16);  // RNE
}

// Kernel 1: zero voxel grid (float4), compute padded cell ids, transpose weight -> bf16 wT[off][n][k].
__global__ __launch_bounds__(256) void k_init(const float* __restrict__ points,
                                              const float* __restrict__ weight,
                                              float* __restrict__ voxgrid,
                                              int* __restrict__ cellid,
                                              unsigned short* __restrict__ wT) {
    int idx = blockIdx.x * 256 + threadIdx.x;
    if (idx < VOXF/4) ((float4*)voxgrid)[idx] = make_float4(0.f, 0.f, 0.f, 0.f);
    if (idx < M) {
        int vx = (int)points[idx*3 + 0];
        int vy = (int)points[idx*3 + 1];
        int vz = (int)points[idx*3 + 2];
        cellid[idx] = (vx + 1)*GD2 + (vy + 1)*GD + (vz + 1);
    }
    if (idx < WTEL) {
        int off = idx >> 13;           // /(128*64)
        int rem = idx & 8191;
        int n   = rem >> 6;
        int k   = rem & 63;
        wT[idx] = f2bf(weight[off*8192 + k*128 + n]);
    }
}

// Kernel 2: scatter-add features into the voxel grid. One thread per (point, cin).
__global__ __launch_bounds__(256) void k_scatter(const float* __restrict__ feat,
                                                 const int* __restrict__ cellid,
                                                 float* __restrict__ voxgrid) {
    int idx = blockIdx.x * 256 + threadIdx.x;   // [0, M*CIN)
    int g   = idx >> 6;
    int cin = idx & 63;
    int b   = g >> 11;
    atomicAdd(&voxgrid[((size_t)b*NCELL + cellid[g])*CIN + cin], feat[idx]);
}

// Kernel 3: MFMA gather-GEMM, software-pipelined over the 27 offsets.
// Block: 16 points x 64 couts, 4 waves; wave = one 16x16 MFMA C-tile, full K.
// Grid: (M/16, 2) = 512 blocks.
__global__ __launch_bounds__(256) void k_gemm(const float* __restrict__ voxgrid,
                                              const int* __restrict__ cellid,
                                              const unsigned short* __restrict__ wT,
                                              const float* __restrict__ bias,
                                              float* __restrict__ out) {
    static constexpr int DELTA[27] = {
        -211,-210,-209,-197,-196,-195,-183,-182,-181,
         -15, -14, -13,  -1,   0,   1,  13,  14,  15,
         181, 182, 183, 195, 196, 197, 209, 210, 211 };

    __shared__ unsigned short Abuf[16*72];   // 16 rows, stride 72 bf16 (144 B) -> 2-way banks only

    const int t   = threadIdx.x;
    const int g0  = blockIdx.x * 16;
    const int b   = g0 >> 11;

    // ---- staging lane role: thread t loads float4 of row (t>>4), cols (t&15)*4 ----
    const int row = t >> 4;
    const int c4  = (t & 15) * 4;
    const int cell = cellid[g0 + row];
    const float* aptr = voxgrid + ((size_t)b*NCELL + cell)*CIN + c4;

    // ---- mfma lane roles ----
    const int l   = t & 63;
    const int w   = t >> 6;
    const int q   = l >> 4;
    const int col = l & 15;
    const int n0  = blockIdx.y * 64 + w * 16;
    const unsigned short* wt0 = wT + (size_t)(n0 + col)*CIN + q*8;   // + off*8192 (+32 for kstep1)
    const unsigned short* abase = &Abuf[(l & 15)*72 + q*8];          // + 32 for kstep1

    f32x4 acc = {0.f, 0.f, 0.f, 0.f};

    // register double-buffer prefetch
    float4 v  = *(const float4*)(aptr + DELTA[0]*CIN);
    us8    b0 = *(const us8*)(wt0);
    us8    b1 = *(const us8*)(wt0 + 32);

    #pragma unroll
    for (int oo = 0; oo < 27; ++oo) {
        __syncthreads();                       // previous compute done with Abuf
        ushort4 pk;
        pk.x = f2bf(v.x); pk.y = f2bf(v.y); pk.z = f2bf(v.z); pk.w = f2bf(v.w);
        *(ushort4*)&Abuf[row*72 + c4] = pk;    // ds_write_b64
        __syncthreads();                       // Abuf visible

        if (oo < 26) {                          // prefetch next offset while computing
            v  = *(const float4*)(aptr + DELTA[oo+1]*CIN);
        }
        us8 b0n, b1n;
        if (oo < 26) {
            b0n = *(const us8*)(wt0 + (oo+1)*8192);
            b1n = *(const us8*)(wt0 + (oo+1)*8192 + 32);
        }

        us8 a0 = *(const us8*)(abase);
        us8 a1 = *(const us8*)(abase + 32);
        acc = __builtin_amdgcn_mfma_f32_16x16x32_bf16(
                  __builtin_bit_cast(bf16x8, a0), __builtin_bit_cast(bf16x8, b0), acc, 0, 0, 0);
        acc = __builtin_amdgcn_mfma_f32_16x16x32_bf16(
                  __builtin_bit_cast(bf16x8, a1), __builtin_bit_cast(bf16x8, b1), acc, 0, 0, 0);

        if (oo < 26) { b0 = b0n; b1 = b1n; }
    }

    // epilogue: C/D layout col = lane&15, row = q*4 + reg; out = acc + bias
    const float bs = bias[n0 + col];
    #pragma unroll
    for (int r = 0; r < 4; ++r) {
        out[(size_t)(g0 + q*4 + r)*COUT + n0 + col] = acc[r] + bs;
    }
}

extern "C" void kernel_launch(void* const* d_in, const int* in_sizes, int n_in,
                              void* d_out, int out_size, void* d_ws, size_t ws_size,
                              hipStream_t stream) {
    (void)in_sizes; (void)n_in; (void)out_size; (void)ws_size;
    const float* points   = (const float*)d_in[0];  // (2,2048,3)
    const float* features = (const float*)d_in[1];  // (2,2048,64)
    const float* weight   = (const float*)d_in[2];  // (3,3,3,64,128)
    const float* bias     = (const float*)d_in[3];  // (128,)
    float* out = (float*)d_out;                     // (2,2048,128)

    float*          voxgrid = (float*)d_ws;                                  // VOXF floats
    int*            cellid  = (int*)((char*)d_ws + (size_t)VOXF*4);          // M ints
    unsigned short* wTp     = (unsigned short*)((char*)d_ws + (size_t)VOXF*4 + (size_t)M*4);

    k_init<<<(WTEL + 255)/256, 256, 0, stream>>>(points, weight, voxgrid, cellid, wTp);
    k_scatter<<<(M*CIN + 255)/256, 256, 0, stream>>>(features, cellid, voxgrid);
    dim3 grid(M/16, 2, 1);
    k_gemm<<<grid, 256, 0, stream>>>(voxgrid, cellid, wTp, bias, out);
}